// Round 1
// baseline (109.073 us; speedup 1.0000x reference)
//
#include <hip/hip_runtime.h>

// Haar IDWT, fully collapsed:
//   out[b, oi, oj] = 0.5 * ( (ll+lh) + sgn_j*hl + sgn_i*sgn_j*hh )
//   coeffs at (b, oi>>1, oj>>1, 0..3); sgn_i=+1 iff oi odd; sgn_j=+1 iff oj odd.
// Symmetric padding in the reference is never sampled after the crop, so no
// boundary handling is needed. Input NHWC C=4 -> one float4 per coeff site.
//
// Thread layout: each thread owns TWO adjacent coefficient sites (x=2*xq, 2*xq+1),
// i.e. a 2(row) x 4(col) output patch. Loads: 2x float4 = 32B/lane contiguous.
// Stores: float4 per output row x 2 rows = 16B/lane contiguous. Both coalesced.

__global__ __launch_bounds__(256) void idwt_haar_kernel(
        const float* __restrict__ in, float* __restrict__ out) {
    int tid = blockIdx.x * 256 + threadIdx.x;
    int xq = tid & 255;          // coefficient column pair index: x = 2*xq, 2*xq+1
    int y  = (tid >> 8) & 511;   // coefficient row
    int b  = tid >> 17;          // batch

    const float4* in4 = reinterpret_cast<const float4*>(in)
                      + ((size_t)(b * 512 + y) * 512 + xq * 2);
    float4 c0 = in4[0];
    float4 c1 = in4[1];

    // c.x=ll, c.y=lh, c.z=hl, c.w=hh  (reference fuses ll+lh by linearity)
    float a0 = c0.x + c0.y, h0 = c0.z, d0 = c0.w;
    float a1 = c1.x + c1.y, h1 = c1.z, d1 = c1.w;

    float4 top, bot;
    // even output row (oi=2y): sgn_i=-1 ; cols: even->sgn_j=-1, odd->sgn_j=+1
    top.x = 0.5f * (a0 - h0 + d0);
    top.y = 0.5f * (a0 + h0 - d0);
    top.z = 0.5f * (a1 - h1 + d1);
    top.w = 0.5f * (a1 + h1 - d1);
    // odd output row (oi=2y+1): sgn_i=+1
    bot.x = 0.5f * (a0 - h0 - d0);
    bot.y = 0.5f * (a0 + h0 + d0);
    bot.z = 0.5f * (a1 - h1 - d1);
    bot.w = 0.5f * (a1 + h1 + d1);

    size_t obase = ((size_t)b * 1024 + 2 * y) * 1024 + 4 * xq;
    *reinterpret_cast<float4*>(out + obase)        = top;
    *reinterpret_cast<float4*>(out + obase + 1024) = bot;
}

extern "C" void kernel_launch(void* const* d_in, const int* in_sizes, int n_in,
                              void* d_out, int out_size, void* d_ws, size_t ws_size,
                              hipStream_t stream) {
    const float* in = (const float*)d_in[0];
    float* out = (float*)d_out;
    // total threads: 16 batches * 512 rows * 256 col-pairs = 2,097,152
    int total = 16 * 512 * 256;
    idwt_haar_kernel<<<total / 256, 256, 0, stream>>>(in, out);
}